// Round 2
// baseline (420.880 us; speedup 1.0000x reference)
//
#include <hip/hip_runtime.h>

// Edge-gather cosine/dot + tiny MLP, fused single kernel.
// Phase A: quarter-wave (16 lanes) per edge gathers 2x256-f32 rows, computes
//          dot, |x1|^2, |x2|^2 with 4-step shfl_xor reduction (width 16).
// Phase B: after 16 A-iters (64 edges staged as (cos,dot) in per-wave LDS),
//          each lane runs the 2->64->32->1 MLP for one edge. MLP weights are
//          wave-uniform -> scalar loads (SGPR operands, scalar pipe).

#define EPS_COS 1e-8f

constexpr int D4 = 64;          // 256 floats = 64 float4
constexpr int BLOCK = 256;
constexpr int WPB = BLOCK / 64; // waves per block

__global__ __launch_bounds__(BLOCK)
void edge_mlp_kernel(const int2* __restrict__ edge,
                     const float* __restrict__ emb,   // [N,256]
                     const float* __restrict__ wvec,  // [256]
                     const float* __restrict__ W1,    // [64,2]
                     const float* __restrict__ b1,    // [64]
                     const float* __restrict__ W2,    // [32,64]
                     const float* __restrict__ b2,    // [32]
                     const float* __restrict__ Wp,    // [32]
                     const float* __restrict__ bp,    // [1]
                     float* __restrict__ out,         // [E]
                     int E)
{
    __shared__ float2 pairs[WPB][64];   // per-wave (cos,dot) staging

    const int lane  = threadIdx.x & 63;
    const int wslot = threadIdx.x >> 6;
    const int gwid  = blockIdx.x * WPB + wslot;
    const int nwaves = gridDim.x * WPB;
    const int q = lane >> 4;   // quarter index: which of 4 edges this iter
    const int t = lane & 15;   // lane within quarter

    // Preload this lane's weight_vec columns (4 chunks of float4).
    float4 wv[4];
    #pragma unroll
    for (int c = 0; c < 4; ++c)
        wv[c] = reinterpret_cast<const float4*>(wvec)[c * 16 + t];

    const int njobs = (E + 63) >> 6;   // 64 edges per wave-job

    for (int job = gwid; job < njobs; job += nwaves) {
        const int ebase = job << 6;

        // One coalesced edge prefetch per job: lane l holds edge[ebase+l].
        const int eidx_mine = ebase + lane;
        int2 eall = (eidx_mine < E) ? edge[eidx_mine] : make_int2(0, 0);

        // ---------------- Phase A: 16 iters x 4 edges ----------------
        for (int s = 0; s < 16; ++s) {
            const int src = s * 4 + q;          // which staged edge this quarter does
            const int ex = __shfl(eall.x, src);
            const int ey = __shfl(eall.y, src);
            const float4* r1 = reinterpret_cast<const float4*>(emb) + (size_t)ex * D4 + t;
            const float4* r2 = reinterpret_cast<const float4*>(emb) + (size_t)ey * D4 + t;

            float dotp = 0.f, n1p = 0.f, n2p = 0.f;
            #pragma unroll
            for (int c = 0; c < 4; ++c) {
                float4 a = r1[c * 16];
                float4 b = r2[c * 16];
                float4 w = wv[c];
                float x1x = a.x * w.x, x1y = a.y * w.y, x1z = a.z * w.z, x1w = a.w * w.w;
                float x2x = b.x * w.x, x2y = b.y * w.y, x2z = b.z * w.z, x2w = b.w * w.w;
                dotp = fmaf(x1x, x2x, fmaf(x1y, x2y, fmaf(x1z, x2z, fmaf(x1w, x2w, dotp))));
                n1p  = fmaf(x1x, x1x, fmaf(x1y, x1y, fmaf(x1z, x1z, fmaf(x1w, x1w, n1p))));
                n2p  = fmaf(x2x, x2x, fmaf(x2y, x2y, fmaf(x2z, x2z, fmaf(x2w, x2w, n2p))));
            }
            // reduce across the 16 lanes of this quarter
            #pragma unroll
            for (int m = 1; m <= 8; m <<= 1) {
                dotp += __shfl_xor(dotp, m, 16);
                n1p  += __shfl_xor(n1p,  m, 16);
                n2p  += __shfl_xor(n2p,  m, 16);
            }
            if (t == 0) {
                float n1 = fmaxf(sqrtf(n1p), EPS_COS);
                float n2 = fmaxf(sqrtf(n2p), EPS_COS);
                float cosv = dotp / (n1 * n2);
                pairs[wslot][src] = make_float2(cosv, dotp);
            }
        }

        // wave-synchronous LDS handoff (same wave; DS ops are in-order per wave)
        __builtin_amdgcn_wave_barrier();
        asm volatile("s_waitcnt lgkmcnt(0)" ::: "memory");

        // ---------------- Phase B: lane-per-edge MLP ----------------
        float2 cd = pairs[wslot][lane];
        float cosv = cd.x, dotv = cd.y;

        // layer 1: 2 -> 64, weights via uniform scalar loads
        float h1[64];
        #pragma unroll
        for (int n = 0; n < 64; ++n)
            h1[n] = fmaxf(fmaf(W1[2 * n], cosv, fmaf(W1[2 * n + 1], dotv, b1[n])), 0.f);

        // layer 2: 64 -> 32, then project to 1
        float pred = bp[0];
        for (int j = 0; j < 32; ++j) {
            const float* w2r = W2 + j * 64;
            float a0 = 0.f, a1 = 0.f, a2 = 0.f, a3 = 0.f;
            #pragma unroll
            for (int k = 0; k < 64; k += 4) {
                a0 = fmaf(w2r[k + 0], h1[k + 0], a0);
                a1 = fmaf(w2r[k + 1], h1[k + 1], a1);
                a2 = fmaf(w2r[k + 2], h1[k + 2], a2);
                a3 = fmaf(w2r[k + 3], h1[k + 3], a3);
            }
            float h2 = fmaxf(b2[j] + ((a0 + a1) + (a2 + a3)), 0.f);
            pred = fmaf(Wp[j], h2, pred);
        }

        const int eo = ebase + lane;
        if (eo < E) out[eo] = pred;
    }
}

extern "C" void kernel_launch(void* const* d_in, const int* in_sizes, int n_in,
                              void* d_out, int out_size, void* d_ws, size_t ws_size,
                              hipStream_t stream) {
    const int2*  edge = (const int2*)d_in[0];
    const float* emb  = (const float*)d_in[1];
    const float* wvec = (const float*)d_in[2];
    const float* W1   = (const float*)d_in[3];
    const float* b1   = (const float*)d_in[4];
    const float* W2   = (const float*)d_in[5];
    const float* b2   = (const float*)d_in[6];
    const float* Wp   = (const float*)d_in[7];
    const float* bp   = (const float*)d_in[8];
    float* out = (float*)d_out;

    const int E = in_sizes[0] / 2;   // edge is [E,2]
    const int grid = 2048;           // multiple of 8 XCDs; grid-stride over wave-jobs

    hipLaunchKernelGGL(edge_mlp_kernel, dim3(grid), dim3(BLOCK), 0, stream,
                       edge, emb, wvec, W1, b1, W2, b2, Wp, bp, out, E);
}

// Round 5
// 325.083 us; speedup vs baseline: 1.2947x; 1.2947x over previous
//
#include <hip/hip_runtime.h>

// Edge-gather cosine/dot + tiny MLP.
// Pass 1: convert emb*weight_vec -> fp16 table in d_ws (halves gather bytes,
//         folds the per-dim weight into the table).
// Pass 2: fused kernel. Phase A: quarter-wave (16 lanes) per edge gathers
//         2x256-fp16 rows (2x16B per lane), accumulates dot/|x1|^2/|x2|^2 in
//         f32 (v_dot2_f32_f16 where available), 4-step shfl_xor reduce.
//         Phase B: lane-per-edge 2->64->32->1 MLP, wave-uniform scalar weights.

#define EPS_COS 1e-8f

constexpr int D = 256;
constexpr int BLOCK = 256;
constexpr int WPB = BLOCK / 64;

typedef _Float16 h2_t __attribute__((ext_vector_type(2)));
typedef _Float16 h8_t __attribute__((ext_vector_type(8)));

#if __has_builtin(__builtin_amdgcn_fdot2)
__device__ inline float fdot2_acc(h2_t a, h2_t b, float c) {
    return __builtin_amdgcn_fdot2(a, b, c, false);
}
#else
__device__ inline float fdot2_acc(h2_t a, h2_t b, float c) {
    return fmaf((float)a[0], (float)b[0], fmaf((float)a[1], (float)b[1], c));
}
#endif

// ---------- Pass 1: scaled fp16 table ----------
__global__ __launch_bounds__(BLOCK)
void scale_half_kernel(const float* __restrict__ emb,
                       const float* __restrict__ wvec,
                       _Float16* __restrict__ dst, int total8)
{
    const int stride = gridDim.x * blockDim.x;
    for (int i = blockIdx.x * blockDim.x + threadIdx.x; i < total8; i += stride) {
        const float4* src = reinterpret_cast<const float4*>(emb) + (size_t)i * 2;
        float4 a0 = src[0], a1 = src[1];
        const int col8 = i & (D / 8 - 1);          // which 8-elem chunk of the row
        const float4* w = reinterpret_cast<const float4*>(wvec) + col8 * 2;
        float4 w0 = w[0], w1 = w[1];
        h8_t r;
        r[0] = (_Float16)(a0.x * w0.x); r[1] = (_Float16)(a0.y * w0.y);
        r[2] = (_Float16)(a0.z * w0.z); r[3] = (_Float16)(a0.w * w0.w);
        r[4] = (_Float16)(a1.x * w1.x); r[5] = (_Float16)(a1.y * w1.y);
        r[6] = (_Float16)(a1.z * w1.z); r[7] = (_Float16)(a1.w * w1.w);
        *reinterpret_cast<h8_t*>(dst + (size_t)i * 8) = r;
    }
}

// ---------- shared phase B: 2->64->32->1 MLP, wave-uniform scalar weights ----------
__device__ inline float mlp_eval(float cosv, float dotv,
                                 const float* __restrict__ W1,
                                 const float* __restrict__ b1,
                                 const float* __restrict__ W2,
                                 const float* __restrict__ b2,
                                 const float* __restrict__ Wp,
                                 const float* __restrict__ bp)
{
    float h1[64];
    #pragma unroll
    for (int n = 0; n < 64; ++n)
        h1[n] = fmaxf(fmaf(W1[2 * n], cosv, fmaf(W1[2 * n + 1], dotv, b1[n])), 0.f);
    float pred = bp[0];
    for (int j = 0; j < 32; ++j) {
        const float* w2r = W2 + j * 64;
        float a0 = 0.f, a1 = 0.f, a2 = 0.f, a3 = 0.f;
        #pragma unroll
        for (int k = 0; k < 64; k += 4) {
            a0 = fmaf(w2r[k + 0], h1[k + 0], a0);
            a1 = fmaf(w2r[k + 1], h1[k + 1], a1);
            a2 = fmaf(w2r[k + 2], h1[k + 2], a2);
            a3 = fmaf(w2r[k + 3], h1[k + 3], a3);
        }
        float h2 = fmaxf(b2[j] + ((a0 + a1) + (a2 + a3)), 0.f);
        pred = fmaf(Wp[j], h2, pred);
    }
    return pred;
}

// ---------- Pass 2: main kernel (fp16 table) ----------
__global__ __launch_bounds__(BLOCK)
void edge_mlp_half_kernel(const int2* __restrict__ edge,
                          const _Float16* __restrict__ tab,  // [N,256] scaled
                          const float* __restrict__ W1, const float* __restrict__ b1,
                          const float* __restrict__ W2, const float* __restrict__ b2,
                          const float* __restrict__ Wp, const float* __restrict__ bp,
                          float* __restrict__ out, int E)
{
    __shared__ float2 pairs[WPB][64];

    const int lane  = threadIdx.x & 63;
    const int wslot = threadIdx.x >> 6;
    const int gwid  = blockIdx.x * WPB + wslot;
    const int nwaves = gridDim.x * WPB;
    const int q = lane >> 4;
    const int t = lane & 15;

    const int njobs = (E + 63) >> 6;

    for (int job = gwid; job < njobs; job += nwaves) {
        const int ebase = job << 6;
        const int eidx_mine = ebase + lane;
        int2 eall = (eidx_mine < E) ? edge[eidx_mine] : make_int2(0, 0);

        for (int s = 0; s < 16; ++s) {
            const int src = s * 4 + q;
            const int ex = __shfl(eall.x, src);
            const int ey = __shfl(eall.y, src);
            // row = 256 fp16 = 32 chunks of 8; lane t takes chunks t and t+16
            const uint4* r1 = reinterpret_cast<const uint4*>(tab + (size_t)ex * D) + t;
            const uint4* r2 = reinterpret_cast<const uint4*>(tab + (size_t)ey * D) + t;

            float dotp = 0.f, n1p = 0.f, n2p = 0.f;
            #pragma unroll
            for (int c = 0; c < 2; ++c) {
                uint4 qa = r1[c * 16];
                uint4 qb = r2[c * 16];
                h2_t* pa = reinterpret_cast<h2_t*>(&qa);
                h2_t* pb = reinterpret_cast<h2_t*>(&qb);
                #pragma unroll
                for (int k = 0; k < 4; ++k) {
                    dotp = fdot2_acc(pa[k], pb[k], dotp);
                    n1p  = fdot2_acc(pa[k], pa[k], n1p);
                    n2p  = fdot2_acc(pb[k], pb[k], n2p);
                }
            }
            #pragma unroll
            for (int m = 1; m <= 8; m <<= 1) {
                dotp += __shfl_xor(dotp, m, 16);
                n1p  += __shfl_xor(n1p,  m, 16);
                n2p  += __shfl_xor(n2p,  m, 16);
            }
            if (t == 0) {
                float n1 = fmaxf(sqrtf(n1p), EPS_COS);
                float n2 = fmaxf(sqrtf(n2p), EPS_COS);
                pairs[wslot][src] = make_float2(dotp / (n1 * n2), dotp);
            }
        }

        __builtin_amdgcn_wave_barrier();
        asm volatile("s_waitcnt lgkmcnt(0)" ::: "memory");

        float2 cd = pairs[wslot][lane];
        float pred = mlp_eval(cd.x, cd.y, W1, b1, W2, b2, Wp, bp);

        const int eo = ebase + lane;
        if (eo < E) out[eo] = pred;
    }
}

// ---------- fallback: f32 path (if ws too small) ----------
__global__ __launch_bounds__(BLOCK)
void edge_mlp_f32_kernel(const int2* __restrict__ edge,
                         const float* __restrict__ emb,
                         const float* __restrict__ wvec,
                         const float* __restrict__ W1, const float* __restrict__ b1,
                         const float* __restrict__ W2, const float* __restrict__ b2,
                         const float* __restrict__ Wp, const float* __restrict__ bp,
                         float* __restrict__ out, int E)
{
    __shared__ float2 pairs[WPB][64];
    const int lane  = threadIdx.x & 63;
    const int wslot = threadIdx.x >> 6;
    const int gwid  = blockIdx.x * WPB + wslot;
    const int nwaves = gridDim.x * WPB;
    const int q = lane >> 4;
    const int t = lane & 15;

    float4 wv[4];
    #pragma unroll
    for (int c = 0; c < 4; ++c)
        wv[c] = reinterpret_cast<const float4*>(wvec)[c * 16 + t];

    const int njobs = (E + 63) >> 6;
    for (int job = gwid; job < njobs; job += nwaves) {
        const int ebase = job << 6;
        const int eidx_mine = ebase + lane;
        int2 eall = (eidx_mine < E) ? edge[eidx_mine] : make_int2(0, 0);

        for (int s = 0; s < 16; ++s) {
            const int src = s * 4 + q;
            const int ex = __shfl(eall.x, src);
            const int ey = __shfl(eall.y, src);
            const float4* r1 = reinterpret_cast<const float4*>(emb) + (size_t)ex * (D / 4) + t;
            const float4* r2 = reinterpret_cast<const float4*>(emb) + (size_t)ey * (D / 4) + t;

            float dotp = 0.f, n1p = 0.f, n2p = 0.f;
            #pragma unroll
            for (int c = 0; c < 4; ++c) {
                float4 a = r1[c * 16];
                float4 b = r2[c * 16];
                float4 w = wv[c];
                float x1x = a.x * w.x, x1y = a.y * w.y, x1z = a.z * w.z, x1w = a.w * w.w;
                float x2x = b.x * w.x, x2y = b.y * w.y, x2z = b.z * w.z, x2w = b.w * w.w;
                dotp = fmaf(x1x, x2x, fmaf(x1y, x2y, fmaf(x1z, x2z, fmaf(x1w, x2w, dotp))));
                n1p  = fmaf(x1x, x1x, fmaf(x1y, x1y, fmaf(x1z, x1z, fmaf(x1w, x1w, n1p))));
                n2p  = fmaf(x2x, x2x, fmaf(x2y, x2y, fmaf(x2z, x2z, fmaf(x2w, x2w, n2p))));
            }
            #pragma unroll
            for (int m = 1; m <= 8; m <<= 1) {
                dotp += __shfl_xor(dotp, m, 16);
                n1p  += __shfl_xor(n1p,  m, 16);
                n2p  += __shfl_xor(n2p,  m, 16);
            }
            if (t == 0) {
                float n1 = fmaxf(sqrtf(n1p), EPS_COS);
                float n2 = fmaxf(sqrtf(n2p), EPS_COS);
                pairs[wslot][src] = make_float2(dotp / (n1 * n2), dotp);
            }
        }

        __builtin_amdgcn_wave_barrier();
        asm volatile("s_waitcnt lgkmcnt(0)" ::: "memory");

        float2 cd = pairs[wslot][lane];
        float pred = mlp_eval(cd.x, cd.y, W1, b1, W2, b2, Wp, bp);
        const int eo = ebase + lane;
        if (eo < E) out[eo] = pred;
    }
}

extern "C" void kernel_launch(void* const* d_in, const int* in_sizes, int n_in,
                              void* d_out, int out_size, void* d_ws, size_t ws_size,
                              hipStream_t stream) {
    const int2*  edge = (const int2*)d_in[0];
    const float* emb  = (const float*)d_in[1];
    const float* wvec = (const float*)d_in[2];
    const float* W1   = (const float*)d_in[3];
    const float* b1   = (const float*)d_in[4];
    const float* W2   = (const float*)d_in[5];
    const float* b2   = (const float*)d_in[6];
    const float* Wp   = (const float*)d_in[7];
    const float* bp   = (const float*)d_in[8];
    float* out = (float*)d_out;

    const int E = in_sizes[0] / 2;
    const int emb_elems = in_sizes[1];            // N * 256
    const int njobs = (E + 63) >> 6;
    // Each wave gets exactly 2 jobs (perfect balance); cap at full residency.
    int nwaves = (njobs + 1) / 2;
    if (nwaves > 8192) nwaves = 8192;
    const int grid_main = (nwaves + WPB - 1) / WPB;

    const size_t need = (size_t)emb_elems * sizeof(_Float16);
    if (ws_size >= need) {
        _Float16* tab = (_Float16*)d_ws;
        const int total8 = emb_elems / 8;
        int cgrid = (total8 + BLOCK - 1) / BLOCK;
        if (cgrid > 2048) cgrid = 2048;
        hipLaunchKernelGGL(scale_half_kernel, dim3(cgrid), dim3(BLOCK), 0, stream,
                           emb, wvec, tab, total8);
        hipLaunchKernelGGL(edge_mlp_half_kernel, dim3(grid_main), dim3(BLOCK), 0, stream,
                           edge, tab, W1, b1, W2, b2, Wp, bp, out, E);
    } else {
        hipLaunchKernelGGL(edge_mlp_f32_kernel, dim3(grid_main), dim3(BLOCK), 0, stream,
                           edge, emb, wvec, W1, b1, W2, b2, Wp, bp, out, E);
    }
}

// Round 8
// 272.668 us; speedup vs baseline: 1.5436x; 1.1922x over previous
//
#include <hip/hip_runtime.h>

// Edge-gather cosine/dot + tiny MLP.
// Pass 1 (quant): per node-row, compute p = emb*wvec (f32), row max -> int8
//         quantize (25.6 MB table in d_ws), and side[row] = (scale,
//         1/max(||dequant||, eps)) -- so the main kernel never computes norms.
// Pass 2: Phase A: quarter-wave (16 lanes) per edge; each lane loads 16 B of
//         each row (one uint4 = whole 256B row across 16 lanes), 4x sdot4,
//         exact int reduce, dequant by sx*sy, cos = dot*rnx*rny.
//         Phase B: lane-per-edge 2->64->32->1 MLP, wave-uniform scalar weights.

#define EPS_COS 1e-8f

constexpr int D = 256;
constexpr int BLOCK = 256;
constexpr int WPB = BLOCK / 64;

__device__ inline int dot4(int a, int b, int c) {
#if __has_builtin(__builtin_amdgcn_sdot4)
    return __builtin_amdgcn_sdot4(a, b, c, false);
#else
    c += (int)(signed char)(a)       * (int)(signed char)(b);
    c += (int)(signed char)(a >> 8)  * (int)(signed char)(b >> 8);
    c += (int)(signed char)(a >> 16) * (int)(signed char)(b >> 16);
    c += (int)(signed char)(a >> 24) * (int)(signed char)(b >> 24);
    return c;
#endif
}

// ---------- Pass 1: quantize emb*wvec to int8 + per-row (scale, rnorm) ----------
__global__ __launch_bounds__(BLOCK)
void quant_kernel(const float* __restrict__ emb,
                  const float* __restrict__ wvec,
                  unsigned char* __restrict__ qtab,   // [N,256] int8
                  float2* __restrict__ side,          // [N] (scale, rnorm)
                  int N)
{
    const int gq = (blockIdx.x * BLOCK + threadIdx.x) >> 4;  // global quarter = row
    const int t  = threadIdx.x & 15;
    if (gq >= N) return;

    const float4* src = reinterpret_cast<const float4*>(emb) + (size_t)gq * 64;
    const float4* wsc = reinterpret_cast<const float4*>(wvec);

    float p[16];
    #pragma unroll
    for (int c = 0; c < 4; ++c) {
        float4 a = src[4 * t + c];
        float4 w = wsc[4 * t + c];
        p[4 * c + 0] = a.x * w.x; p[4 * c + 1] = a.y * w.y;
        p[4 * c + 2] = a.z * w.z; p[4 * c + 3] = a.w * w.w;
    }

    float m = 0.f;
    #pragma unroll
    for (int i = 0; i < 16; ++i) m = fmaxf(m, fabsf(p[i]));
    #pragma unroll
    for (int mask = 1; mask <= 8; mask <<= 1) m = fmaxf(m, __shfl_xor(m, mask, 16));

    const float inv_s = (m > 0.f) ? 127.f / m : 0.f;
    const float s     = m * (1.f / 127.f);

    float ss = 0.f;
    unsigned int bw[4];
    #pragma unroll
    for (int c = 0; c < 4; ++c) {
        unsigned int w = 0;
        #pragma unroll
        for (int k = 0; k < 4; ++k) {
            float v = rintf(p[4 * c + k] * inv_s);
            v = fminf(127.f, fmaxf(-127.f, v));
            ss = fmaf(v, v, ss);
            int qv = (int)v;
            w |= ((unsigned int)(qv & 0xff)) << (8 * k);
        }
        bw[c] = w;
    }
    *reinterpret_cast<uint4*>(qtab + (size_t)gq * D + t * 16) =
        make_uint4(bw[0], bw[1], bw[2], bw[3]);

    #pragma unroll
    for (int mask = 1; mask <= 8; mask <<= 1) ss += __shfl_xor(ss, mask, 16);
    if (t == 0) {
        float n = s * sqrtf(ss);                    // || dequantized row ||
        side[gq] = make_float2(s, 1.f / fmaxf(n, EPS_COS));
    }
}

// ---------- shared phase B: 2->64->32->1 MLP, wave-uniform scalar weights ----------
__device__ inline float mlp_eval(float cosv, float dotv,
                                 const float* __restrict__ W1,
                                 const float* __restrict__ b1,
                                 const float* __restrict__ W2,
                                 const float* __restrict__ b2,
                                 const float* __restrict__ Wp,
                                 const float* __restrict__ bp)
{
    float h1[64];
    #pragma unroll
    for (int n = 0; n < 64; ++n)
        h1[n] = fmaxf(fmaf(W1[2 * n], cosv, fmaf(W1[2 * n + 1], dotv, b1[n])), 0.f);
    float pred = bp[0];
    for (int j = 0; j < 32; ++j) {
        const float* w2r = W2 + j * 64;
        float a0 = 0.f, a1 = 0.f, a2 = 0.f, a3 = 0.f;
        #pragma unroll
        for (int k = 0; k < 64; k += 4) {
            a0 = fmaf(w2r[k + 0], h1[k + 0], a0);
            a1 = fmaf(w2r[k + 1], h1[k + 1], a1);
            a2 = fmaf(w2r[k + 2], h1[k + 2], a2);
            a3 = fmaf(w2r[k + 3], h1[k + 3], a3);
        }
        float h2 = fmaxf(b2[j] + ((a0 + a1) + (a2 + a3)), 0.f);
        pred = fmaf(Wp[j], h2, pred);
    }
    return pred;
}

// ---------- Pass 2: main kernel (int8 table + side norms) ----------
__global__ __launch_bounds__(BLOCK)
void edge_mlp_i8_kernel(const int2* __restrict__ edge,
                        const unsigned char* __restrict__ qtab,  // [N,256] int8
                        const float2* __restrict__ side,         // [N] (s, rn)
                        const float* __restrict__ W1, const float* __restrict__ b1,
                        const float* __restrict__ W2, const float* __restrict__ b2,
                        const float* __restrict__ Wp, const float* __restrict__ bp,
                        float* __restrict__ out, int E)
{
    __shared__ float2 pairs[WPB][64];

    const int lane  = threadIdx.x & 63;
    const int wslot = threadIdx.x >> 6;
    const int gwid  = blockIdx.x * WPB + wslot;
    const int nwaves = gridDim.x * WPB;
    const int q = lane >> 4;
    const int t = lane & 15;

    const int njobs = (E + 63) >> 6;

    for (int job = gwid; job < njobs; job += nwaves) {
        const int ebase = job << 6;
        const int eidx_mine = ebase + lane;
        int2 eall = (eidx_mine < E) ? edge[eidx_mine] : make_int2(0, 0);

        // prolog: load s=0 rows + scales
        int ex = __shfl(eall.x, q);
        int ey = __shfl(eall.y, q);
        uint4  qa = reinterpret_cast<const uint4*>(qtab + (size_t)ex * D)[t];
        uint4  qb = reinterpret_cast<const uint4*>(qtab + (size_t)ey * D)[t];
        float2 sx = side[ex];
        float2 sy = side[ey];

        for (int s = 0; s < 16; ++s) {
            // prefetch next iteration's rows + scales
            uint4 nqa = make_uint4(0, 0, 0, 0), nqb = make_uint4(0, 0, 0, 0);
            float2 nsx = make_float2(0.f, 0.f), nsy = make_float2(0.f, 0.f);
            if (s < 15) {
                const int src2 = (s + 1) * 4 + q;
                const int ex2 = __shfl(eall.x, src2);
                const int ey2 = __shfl(eall.y, src2);
                nqa = reinterpret_cast<const uint4*>(qtab + (size_t)ex2 * D)[t];
                nqb = reinterpret_cast<const uint4*>(qtab + (size_t)ey2 * D)[t];
                nsx = side[ex2];
                nsy = side[ey2];
            }

            // current dot (exact int)
            int d = 0;
            d = dot4(qa.x, qb.x, d);
            d = dot4(qa.y, qb.y, d);
            d = dot4(qa.z, qb.z, d);
            d = dot4(qa.w, qb.w, d);
            #pragma unroll
            for (int mask = 1; mask <= 8; mask <<= 1) d += __shfl_xor(d, mask, 16);

            const float dotf = (float)d * sx.x * sy.x;
            const float cosv = dotf * sx.y * sy.y;
            if (t == 0) pairs[wslot][s * 4 + q] = make_float2(cosv, dotf);

            qa = nqa; qb = nqb; sx = nsx; sy = nsy;
        }

        __builtin_amdgcn_wave_barrier();
        asm volatile("s_waitcnt lgkmcnt(0)" ::: "memory");

        float2 cd = pairs[wslot][lane];
        float pred = mlp_eval(cd.x, cd.y, W1, b1, W2, b2, Wp, bp);

        const int eo = ebase + lane;
        if (eo < E) out[eo] = pred;
    }
}

// ---------- fallback: f32 path (if ws too small) ----------
__global__ __launch_bounds__(BLOCK)
void edge_mlp_f32_kernel(const int2* __restrict__ edge,
                         const float* __restrict__ emb,
                         const float* __restrict__ wvec,
                         const float* __restrict__ W1, const float* __restrict__ b1,
                         const float* __restrict__ W2, const float* __restrict__ b2,
                         const float* __restrict__ Wp, const float* __restrict__ bp,
                         float* __restrict__ out, int E)
{
    __shared__ float2 pairs[WPB][64];
    const int lane  = threadIdx.x & 63;
    const int wslot = threadIdx.x >> 6;
    const int gwid  = blockIdx.x * WPB + wslot;
    const int nwaves = gridDim.x * WPB;
    const int q = lane >> 4;
    const int t = lane & 15;

    float4 wv[4];
    #pragma unroll
    for (int c = 0; c < 4; ++c)
        wv[c] = reinterpret_cast<const float4*>(wvec)[c * 16 + t];

    const int njobs = (E + 63) >> 6;
    for (int job = gwid; job < njobs; job += nwaves) {
        const int ebase = job << 6;
        const int eidx_mine = ebase + lane;
        int2 eall = (eidx_mine < E) ? edge[eidx_mine] : make_int2(0, 0);

        for (int s = 0; s < 16; ++s) {
            const int src = s * 4 + q;
            const int ex = __shfl(eall.x, src);
            const int ey = __shfl(eall.y, src);
            const float4* r1 = reinterpret_cast<const float4*>(emb) + (size_t)ex * (D / 4) + t;
            const float4* r2 = reinterpret_cast<const float4*>(emb) + (size_t)ey * (D / 4) + t;

            float dotp = 0.f, n1p = 0.f, n2p = 0.f;
            #pragma unroll
            for (int c = 0; c < 4; ++c) {
                float4 a = r1[c * 16];
                float4 b = r2[c * 16];
                float4 w = wv[c];
                float x1x = a.x * w.x, x1y = a.y * w.y, x1z = a.z * w.z, x1w = a.w * w.w;
                float x2x = b.x * w.x, x2y = b.y * w.y, x2z = b.z * w.z, x2w = b.w * w.w;
                dotp = fmaf(x1x, x2x, fmaf(x1y, x2y, fmaf(x1z, x2z, fmaf(x1w, x2w, dotp))));
                n1p  = fmaf(x1x, x1x, fmaf(x1y, x1y, fmaf(x1z, x1z, fmaf(x1w, x1w, n1p))));
                n2p  = fmaf(x2x, x2x, fmaf(x2y, x2y, fmaf(x2z, x2z, fmaf(x2w, x2w, n2p))));
            }
            #pragma unroll
            for (int m = 1; m <= 8; m <<= 1) {
                dotp += __shfl_xor(dotp, m, 16);
                n1p  += __shfl_xor(n1p,  m, 16);
                n2p  += __shfl_xor(n2p,  m, 16);
            }
            if (t == 0) {
                float n1 = fmaxf(sqrtf(n1p), EPS_COS);
                float n2 = fmaxf(sqrtf(n2p), EPS_COS);
                pairs[wslot][src] = make_float2(dotp / (n1 * n2), dotp);
            }
        }

        __builtin_amdgcn_wave_barrier();
        asm volatile("s_waitcnt lgkmcnt(0)" ::: "memory");

        float2 cd = pairs[wslot][lane];
        float pred = mlp_eval(cd.x, cd.y, W1, b1, W2, b2, Wp, bp);
        const int eo = ebase + lane;
        if (eo < E) out[eo] = pred;
    }
}

extern "C" void kernel_launch(void* const* d_in, const int* in_sizes, int n_in,
                              void* d_out, int out_size, void* d_ws, size_t ws_size,
                              hipStream_t stream) {
    const int2*  edge = (const int2*)d_in[0];
    const float* emb  = (const float*)d_in[1];
    const float* wvec = (const float*)d_in[2];
    const float* W1   = (const float*)d_in[3];
    const float* b1   = (const float*)d_in[4];
    const float* W2   = (const float*)d_in[5];
    const float* b2   = (const float*)d_in[6];
    const float* Wp   = (const float*)d_in[7];
    const float* bp   = (const float*)d_in[8];
    float* out = (float*)d_out;

    const int E = in_sizes[0] / 2;
    const int emb_elems = in_sizes[1];            // N * 256
    const int N = emb_elems / D;
    const int njobs = (E + 63) >> 6;
    int nwaves = (njobs + 1) / 2;                  // 2 jobs per wave, balanced
    if (nwaves > 8192) nwaves = 8192;
    const int grid_main = (nwaves + WPB - 1) / WPB;

    // ws layout: int8 table (N*256 B, 256-aligned) + side table (N * float2)
    const size_t qtab_bytes = ((size_t)emb_elems + 255) & ~(size_t)255;
    const size_t need = qtab_bytes + (size_t)N * sizeof(float2);

    if (ws_size >= need) {
        unsigned char* qtab = (unsigned char*)d_ws;
        float2* side = (float2*)((char*)d_ws + qtab_bytes);
        const int qgrid = (N * 16 + BLOCK - 1) / BLOCK;
        hipLaunchKernelGGL(quant_kernel, dim3(qgrid), dim3(BLOCK), 0, stream,
                           emb, wvec, qtab, side, N);
        hipLaunchKernelGGL(edge_mlp_i8_kernel, dim3(grid_main), dim3(BLOCK), 0, stream,
                           edge, qtab, side, W1, b1, W2, b2, Wp, bp, out, E);
    } else {
        hipLaunchKernelGGL(edge_mlp_f32_kernel, dim3(grid_main), dim3(BLOCK), 0, stream,
                           edge, emb, wvec, W1, b1, W2, b2, Wp, bp, out, E);
    }
}

// Round 10
// 270.059 us; speedup vs baseline: 1.5585x; 1.0097x over previous
//
#include <hip/hip_runtime.h>

// Edge-gather cosine/dot + tiny MLP.
// Pass 1 (quant): per node-row, compute p = emb*wvec (f32), row max -> int8
//         quantize (25.6 MB table in d_ws), and side[row] = (scale,
//         1/max(||dequant||, eps)) -- main kernel never computes norms.
// Pass 2: Phase A: quarter-wave (16 lanes) per edge; 3-stage software pipeline
//         (issue loads for iter s+2 while computing iter s) to double the
//         bytes-in-flight per wave vs the 1-deep version (R8: 2.2 TB/s, dur
//         112us was MLP-limited). 4x sdot4, exact int reduce, dequant.
//         Phase B: lane-per-edge 2->64->32->1 MLP, wave-uniform scalar weights.

#define EPS_COS 1e-8f

constexpr int D = 256;
constexpr int BLOCK = 256;
constexpr int WPB = BLOCK / 64;

__device__ inline int dot4(int a, int b, int c) {
#if __has_builtin(__builtin_amdgcn_sdot4)
    return __builtin_amdgcn_sdot4(a, b, c, false);
#else
    c += (int)(signed char)(a)       * (int)(signed char)(b);
    c += (int)(signed char)(a >> 8)  * (int)(signed char)(b >> 8);
    c += (int)(signed char)(a >> 16) * (int)(signed char)(b >> 16);
    c += (int)(signed char)(a >> 24) * (int)(signed char)(b >> 24);
    return c;
#endif
}

// ---------- Pass 1: quantize emb*wvec to int8 + per-row (scale, rnorm) ----------
__global__ __launch_bounds__(BLOCK)
void quant_kernel(const float* __restrict__ emb,
                  const float* __restrict__ wvec,
                  unsigned char* __restrict__ qtab,   // [N,256] int8
                  float2* __restrict__ side,          // [N] (scale, rnorm)
                  int N)
{
    const int gq = (blockIdx.x * BLOCK + threadIdx.x) >> 4;  // global quarter = row
    const int t  = threadIdx.x & 15;
    if (gq >= N) return;

    const float4* src = reinterpret_cast<const float4*>(emb) + (size_t)gq * 64;
    const float4* wsc = reinterpret_cast<const float4*>(wvec);

    float p[16];
    #pragma unroll
    for (int c = 0; c < 4; ++c) {
        float4 a = src[4 * t + c];
        float4 w = wsc[4 * t + c];
        p[4 * c + 0] = a.x * w.x; p[4 * c + 1] = a.y * w.y;
        p[4 * c + 2] = a.z * w.z; p[4 * c + 3] = a.w * w.w;
    }

    float m = 0.f;
    #pragma unroll
    for (int i = 0; i < 16; ++i) m = fmaxf(m, fabsf(p[i]));
    #pragma unroll
    for (int mask = 1; mask <= 8; mask <<= 1) m = fmaxf(m, __shfl_xor(m, mask, 16));

    const float inv_s = (m > 0.f) ? 127.f / m : 0.f;
    const float s     = m * (1.f / 127.f);

    float ss = 0.f;
    unsigned int bw[4];
    #pragma unroll
    for (int c = 0; c < 4; ++c) {
        unsigned int w = 0;
        #pragma unroll
        for (int k = 0; k < 4; ++k) {
            float v = rintf(p[4 * c + k] * inv_s);
            v = fminf(127.f, fmaxf(-127.f, v));
            ss = fmaf(v, v, ss);
            int qv = (int)v;
            w |= ((unsigned int)(qv & 0xff)) << (8 * k);
        }
        bw[c] = w;
    }
    *reinterpret_cast<uint4*>(qtab + (size_t)gq * D + t * 16) =
        make_uint4(bw[0], bw[1], bw[2], bw[3]);

    #pragma unroll
    for (int mask = 1; mask <= 8; mask <<= 1) ss += __shfl_xor(ss, mask, 16);
    if (t == 0) {
        float n = s * sqrtf(ss);                    // || dequantized row ||
        side[gq] = make_float2(s, 1.f / fmaxf(n, EPS_COS));
    }
}

// ---------- shared phase B: 2->64->32->1 MLP, wave-uniform scalar weights ----------
__device__ inline float mlp_eval(float cosv, float dotv,
                                 const float* __restrict__ W1,
                                 const float* __restrict__ b1,
                                 const float* __restrict__ W2,
                                 const float* __restrict__ b2,
                                 const float* __restrict__ Wp,
                                 const float* __restrict__ bp)
{
    float h1[64];
    #pragma unroll
    for (int n = 0; n < 64; ++n)
        h1[n] = fmaxf(fmaf(W1[2 * n], cosv, fmaf(W1[2 * n + 1], dotv, b1[n])), 0.f);
    float pred = bp[0];
    for (int j = 0; j < 32; ++j) {
        const float* w2r = W2 + j * 64;
        float a0 = 0.f, a1 = 0.f, a2 = 0.f, a3 = 0.f;
        #pragma unroll
        for (int k = 0; k < 64; k += 4) {
            a0 = fmaf(w2r[k + 0], h1[k + 0], a0);
            a1 = fmaf(w2r[k + 1], h1[k + 1], a1);
            a2 = fmaf(w2r[k + 2], h1[k + 2], a2);
            a3 = fmaf(w2r[k + 3], h1[k + 3], a3);
        }
        float h2 = fmaxf(b2[j] + ((a0 + a1) + (a2 + a3)), 0.f);
        pred = fmaf(Wp[j], h2, pred);
    }
    return pred;
}

// ---------- Pass 2: main kernel (int8 table, 3-stage pipelined gather) ----------
__global__ __launch_bounds__(BLOCK)
void edge_mlp_i8_kernel(const int2* __restrict__ edge,
                        const unsigned char* __restrict__ qtab,  // [N,256] int8
                        const float2* __restrict__ side,         // [N] (s, rn)
                        const float* __restrict__ W1, const float* __restrict__ b1,
                        const float* __restrict__ W2, const float* __restrict__ b2,
                        const float* __restrict__ Wp, const float* __restrict__ bp,
                        float* __restrict__ out, int E)
{
    __shared__ float2 pairs[WPB][64];

    const int lane  = threadIdx.x & 63;
    const int wslot = threadIdx.x >> 6;
    const int gwid  = blockIdx.x * WPB + wslot;
    const int nwaves = gridDim.x * WPB;
    const int q = lane >> 4;
    const int t = lane & 15;

    const int njobs = (E + 63) >> 6;

    for (int job = gwid; job < njobs; job += nwaves) {
        const int ebase = job << 6;
        const int eidx_mine = ebase + lane;
        int2 eall = (eidx_mine < E) ? edge[eidx_mine] : make_int2(0, 0);

        // 3-slot register ring; indices are compile-time after full unroll.
        uint4  qa[3], qb[3];
        float2 sx[3], sy[3];

#define ISSUE_STAGE(st, ss)                                                   \
        {                                                                     \
            const int ex_ = __shfl(eall.x, (ss) * 4 + q);                     \
            const int ey_ = __shfl(eall.y, (ss) * 4 + q);                     \
            qa[st] = reinterpret_cast<const uint4*>(qtab + (size_t)ex_ * D)[t]; \
            qb[st] = reinterpret_cast<const uint4*>(qtab + (size_t)ey_ * D)[t]; \
            sx[st] = side[ex_];                                               \
            sy[st] = side[ey_];                                               \
        }

        ISSUE_STAGE(0, 0)
        ISSUE_STAGE(1, 1)

        #pragma unroll
        for (int s = 0; s < 16; ++s) {
            const int cur = s % 3;
            if (s + 2 < 16) {
                const int nxt = (s + 2) % 3;
                ISSUE_STAGE(nxt, s + 2)
            }

            // current dot (exact int)
            int d = 0;
            d = dot4(qa[cur].x, qb[cur].x, d);
            d = dot4(qa[cur].y, qb[cur].y, d);
            d = dot4(qa[cur].z, qb[cur].z, d);
            d = dot4(qa[cur].w, qb[cur].w, d);
            #pragma unroll
            for (int mask = 1; mask <= 8; mask <<= 1) d += __shfl_xor(d, mask, 16);

            const float dotf = (float)d * sx[cur].x * sy[cur].x;
            const float cosv = dotf * sx[cur].y * sy[cur].y;
            if (t == 0) pairs[wslot][s * 4 + q] = make_float2(cosv, dotf);
        }
#undef ISSUE_STAGE

        __builtin_amdgcn_wave_barrier();
        asm volatile("s_waitcnt lgkmcnt(0)" ::: "memory");

        float2 cd = pairs[wslot][lane];
        float pred = mlp_eval(cd.x, cd.y, W1, b1, W2, b2, Wp, bp);

        const int eo = ebase + lane;
        if (eo < E) out[eo] = pred;
    }
}

// ---------- fallback: f32 path (if ws too small) ----------
__global__ __launch_bounds__(BLOCK)
void edge_mlp_f32_kernel(const int2* __restrict__ edge,
                         const float* __restrict__ emb,
                         const float* __restrict__ wvec,
                         const float* __restrict__ W1, const float* __restrict__ b1,
                         const float* __restrict__ W2, const float* __restrict__ b2,
                         const float* __restrict__ Wp, const float* __restrict__ bp,
                         float* __restrict__ out, int E)
{
    __shared__ float2 pairs[WPB][64];
    const int lane  = threadIdx.x & 63;
    const int wslot = threadIdx.x >> 6;
    const int gwid  = blockIdx.x * WPB + wslot;
    const int nwaves = gridDim.x * WPB;
    const int q = lane >> 4;
    const int t = lane & 15;

    float4 wv[4];
    #pragma unroll
    for (int c = 0; c < 4; ++c)
        wv[c] = reinterpret_cast<const float4*>(wvec)[c * 16 + t];

    const int njobs = (E + 63) >> 6;
    for (int job = gwid; job < njobs; job += nwaves) {
        const int ebase = job << 6;
        const int eidx_mine = ebase + lane;
        int2 eall = (eidx_mine < E) ? edge[eidx_mine] : make_int2(0, 0);

        for (int s = 0; s < 16; ++s) {
            const int src = s * 4 + q;
            const int ex = __shfl(eall.x, src);
            const int ey = __shfl(eall.y, src);
            const float4* r1 = reinterpret_cast<const float4*>(emb) + (size_t)ex * (D / 4) + t;
            const float4* r2 = reinterpret_cast<const float4*>(emb) + (size_t)ey * (D / 4) + t;

            float dotp = 0.f, n1p = 0.f, n2p = 0.f;
            #pragma unroll
            for (int c = 0; c < 4; ++c) {
                float4 a = r1[c * 16];
                float4 b = r2[c * 16];
                float4 w = wv[c];
                float x1x = a.x * w.x, x1y = a.y * w.y, x1z = a.z * w.z, x1w = a.w * w.w;
                float x2x = b.x * w.x, x2y = b.y * w.y, x2z = b.z * w.z, x2w = b.w * w.w;
                dotp = fmaf(x1x, x2x, fmaf(x1y, x2y, fmaf(x1z, x2z, fmaf(x1w, x2w, dotp))));
                n1p  = fmaf(x1x, x1x, fmaf(x1y, x1y, fmaf(x1z, x1z, fmaf(x1w, x1w, n1p))));
                n2p  = fmaf(x2x, x2x, fmaf(x2y, x2y, fmaf(x2z, x2z, fmaf(x2w, x2w, n2p))));
            }
            #pragma unroll
            for (int m = 1; m <= 8; m <<= 1) {
                dotp += __shfl_xor(dotp, m, 16);
                n1p  += __shfl_xor(n1p,  m, 16);
                n2p  += __shfl_xor(n2p,  m, 16);
            }
            if (t == 0) {
                float n1 = fmaxf(sqrtf(n1p), EPS_COS);
                float n2 = fmaxf(sqrtf(n2p), EPS_COS);
                pairs[wslot][src] = make_float2(dotp / (n1 * n2), dotp);
            }
        }

        __builtin_amdgcn_wave_barrier();
        asm volatile("s_waitcnt lgkmcnt(0)" ::: "memory");

        float2 cd = pairs[wslot][lane];
        float pred = mlp_eval(cd.x, cd.y, W1, b1, W2, b2, Wp, bp);
        const int eo = ebase + lane;
        if (eo < E) out[eo] = pred;
    }
}

extern "C" void kernel_launch(void* const* d_in, const int* in_sizes, int n_in,
                              void* d_out, int out_size, void* d_ws, size_t ws_size,
                              hipStream_t stream) {
    const int2*  edge = (const int2*)d_in[0];
    const float* emb  = (const float*)d_in[1];
    const float* wvec = (const float*)d_in[2];
    const float* W1   = (const float*)d_in[3];
    const float* b1   = (const float*)d_in[4];
    const float* W2   = (const float*)d_in[5];
    const float* b2   = (const float*)d_in[6];
    const float* Wp   = (const float*)d_in[7];
    const float* bp   = (const float*)d_in[8];
    float* out = (float*)d_out;

    const int E = in_sizes[0] / 2;
    const int emb_elems = in_sizes[1];            // N * 256
    const int N = emb_elems / D;
    const int njobs = (E + 63) >> 6;
    int nwaves = (njobs + 1) / 2;                  // 2 jobs per wave, balanced
    if (nwaves > 8192) nwaves = 8192;
    const int grid_main = (nwaves + WPB - 1) / WPB;

    // ws layout: int8 table (N*256 B, 256-aligned) + side table (N * float2)
    const size_t qtab_bytes = ((size_t)emb_elems + 255) & ~(size_t)255;
    const size_t need = qtab_bytes + (size_t)N * sizeof(float2);

    if (ws_size >= need) {
        unsigned char* qtab = (unsigned char*)d_ws;
        float2* side = (float2*)((char*)d_ws + qtab_bytes);
        const int qgrid = (N * 16 + BLOCK - 1) / BLOCK;
        hipLaunchKernelGGL(quant_kernel, dim3(qgrid), dim3(BLOCK), 0, stream,
                           emb, wvec, qtab, side, N);
        hipLaunchKernelGGL(edge_mlp_i8_kernel, dim3(grid_main), dim3(BLOCK), 0, stream,
                           edge, qtab, side, W1, b1, W2, b2, Wp, bp, out, E);
    } else {
        hipLaunchKernelGGL(edge_mlp_f32_kernel, dim3(grid_main), dim3(BLOCK), 0, stream,
                           edge, emb, wvec, W1, b1, W2, b2, Wp, bp, out, E);
    }
}